// Round 1
// 141.029 us; speedup vs baseline: 1.0608x; 1.0608x over previous
//
#include <hip/hip_runtime.h>

#define NCB 32
#define KK 16
#define DD 128
#define IN_F 4096
#define OUT_F 2048
#define NTOK 2048

// ---- Launch A geometry ----
// LUT: 32 c x 2 k-half x 2 o-half = 128 blocks, thread owns 4 consecutive o.
#define LUT_BLOCKS 128
// IDX: 32 tokens per block (was 64) -> LDS 28.75 KB -> 5 blocks/CU LDS ceiling.
#define TT 32
#define IDX_BLOCKS ((NTOK / TT) * NCB)  // 2048

// LDS layout for idx branch (floats): xs[TT][148] then cs[16][164]
#define XS_STRIDE 148
#define CS_OFF (TT * XS_STRIDE)
#define SMEM_FLOATS (CS_OFF + KK * 164)  // 7360 floats = 28.75 KB

// ---- Launch A: grid-partitioned fusion of lut-build and idx-argmin ----
__global__ __launch_bounds__(256, 4) void fused_lut_idx(
    const float* __restrict__ centroids, const float* __restrict__ weight,
    const float* __restrict__ x, const float* __restrict__ bias,
    float* __restrict__ lut, unsigned char* __restrict__ idxb) {
    __shared__ float smem[SMEM_FLOATS];
    const int tid = threadIdx.x;

    if (blockIdx.x < LUT_BLOCKS) {
        // lut[c][k][o] = sum_d cent[c][k][d] * W[c][d][o]  (+ bias[o] for c==0)
        // Thread owns 4 consecutive o -> float4 weight loads (1 KB/wave/instr).
        // k-split x2 keeps acc at 8 float4 (32 VGPR) and halves the VALU tail.
        const int c  = blockIdx.x >> 2;
        const int kh = (blockIdx.x >> 1) & 1;  // k in [kh*8, kh*8+8)
        const int oh = blockIdx.x & 1;
        const int o  = oh * 1024 + tid * 4;
        const float* cb = centroids + ((size_t)c * KK + kh * 8) * DD;
        const float* wb = weight + (size_t)c * DD * OUT_F + o;
        float4 acc[8];
#pragma unroll
        for (int k = 0; k < 8; ++k) acc[k] = make_float4(0.f, 0.f, 0.f, 0.f);
#pragma unroll 2
        for (int d4 = 0; d4 < DD / 4; ++d4) {
            float4 w0 = *(const float4*)(wb + (size_t)(d4 * 4 + 0) * OUT_F);
            float4 w1 = *(const float4*)(wb + (size_t)(d4 * 4 + 1) * OUT_F);
            float4 w2 = *(const float4*)(wb + (size_t)(d4 * 4 + 2) * OUT_F);
            float4 w3 = *(const float4*)(wb + (size_t)(d4 * 4 + 3) * OUT_F);
#pragma unroll
            for (int k = 0; k < 8; ++k) {
                float4 cv = *(const float4*)(cb + k * DD + d4 * 4);  // uniform
                acc[k].x += cv.x * w0.x + cv.y * w1.x + cv.z * w2.x + cv.w * w3.x;
                acc[k].y += cv.x * w0.y + cv.y * w1.y + cv.z * w2.y + cv.w * w3.y;
                acc[k].z += cv.x * w0.z + cv.y * w1.z + cv.z * w2.z + cv.w * w3.z;
                acc[k].w += cv.x * w0.w + cv.y * w1.w + cv.z * w2.w + cv.w * w3.w;
            }
        }
        if (c == 0) {  // fold bias into lut[0][*][*]; exactly one k per c is
            float4 bv = *(const float4*)(bias + o);  // gathered -> bias once.
#pragma unroll
            for (int k = 0; k < 8; ++k) {
                acc[k].x += bv.x; acc[k].y += bv.y;
                acc[k].z += bv.z; acc[k].w += bv.w;
            }
        }
#pragma unroll
        for (int k = 0; k < 8; ++k)
            *(float4*)(lut + ((size_t)c * KK + kh * 8 + k) * OUT_F + o) = acc[k];
    } else {
        // idx[t][c] = argmin_k (|cent[c][k]|^2 - 2 x[t].cent[c][k])
        // Same arithmetic as previous version; token tile halved to 32.
        const int bid = blockIdx.x - LUT_BLOCKS;
        const int c = bid & (NCB - 1);
        const int t0 = (bid >> 5) * TT;
        const int th_q = tid & 3;
        const int th_k = (tid >> 2) & 3;
        const int th_t = tid >> 4;  // 0..15, each handles 2 tokens
        float* xs = smem;            // [TT][148], segment layout q*36+j
        float* cs = smem + CS_OFF;   // [16][164], layout q*40+j

        // stage x tile: 32 tokens x 128 floats (c-slice), coalesced.
        {
            const float* xg = x + (size_t)t0 * IN_F + c * DD;
#pragma unroll
            for (int i = 0; i < (TT * DD / 4) / 256; ++i) {  // 4 iters
                int p = i * 256 + tid;           // float4 index
                int t = p >> 5, f4 = p & 31;
                int q = f4 >> 3, jj = f4 & 7;
                float4 v = *(const float4*)(xg + (size_t)t * IN_F + f4 * 4);
                *(float4*)(xs + t * XS_STRIDE + q * 36 + jj * 4) = v;
            }
        }
        // stage centroids (8 KB)
        for (int p = tid; p < KK * 32; p += 256) {
            int k = p >> 5, f4 = p & 31;
            int q = f4 >> 3, jj = f4 & 7;
            *(float4*)(cs + k * 164 + q * 40 + jj * 4) =
                *(const float4*)(centroids + ((size_t)c * KK + k) * DD + f4 * 4);
        }
        __syncthreads();

        float acc[2][4], sq[4];
#pragma unroll
        for (int r = 0; r < 2; ++r)
#pragma unroll
            for (int kk = 0; kk < 4; ++kk) acc[r][kk] = 0.f;
#pragma unroll
        for (int kk = 0; kk < 4; ++kk) sq[kk] = 0.f;

#pragma unroll
        for (int chunk = 0; chunk < 8; ++chunk) {
            float4 ca[4];
#pragma unroll
            for (int kk = 0; kk < 4; ++kk)
                ca[kk] = *(const float4*)(cs + (th_k * 4 + kk) * 164 + th_q * 40 + chunk * 4);
#pragma unroll
            for (int kk = 0; kk < 4; ++kk)
                sq[kk] += ca[kk].x * ca[kk].x + ca[kk].y * ca[kk].y
                        + ca[kk].z * ca[kk].z + ca[kk].w * ca[kk].w;
#pragma unroll
            for (int r = 0; r < 2; ++r) {
                float4 xr = *(const float4*)(xs + (th_t * 2 + r) * XS_STRIDE
                                             + th_q * 36 + chunk * 4);
#pragma unroll
                for (int kk = 0; kk < 4; ++kk)
                    acc[r][kk] += xr.x * ca[kk].x + xr.y * ca[kk].y
                                + xr.z * ca[kk].z + xr.w * ca[kk].w;
            }
        }
#pragma unroll
        for (int kk = 0; kk < 4; ++kk) {
            float a = sq[kk];
            a += __shfl_xor(a, 1);
            a += __shfl_xor(a, 2);
            sq[kk] = a;
        }
#pragma unroll
        for (int r = 0; r < 2; ++r)
#pragma unroll
            for (int kk = 0; kk < 4; ++kk) {
                float a = acc[r][kk];
                a += __shfl_xor(a, 1);
                a += __shfl_xor(a, 2);
                acc[r][kk] = a;
            }
#pragma unroll
        for (int r = 0; r < 2; ++r) {
            float best = sq[0] - 2.f * acc[r][0];
            int bi = th_k * 4;
#pragma unroll
            for (int kk = 1; kk < 4; ++kk) {
                float v = sq[kk] - 2.f * acc[r][kk];
                if (v < best) { best = v; bi = th_k * 4 + kk; }
            }
#pragma unroll
            for (int s = 4; s <= 8; s <<= 1) {
                float ov = __shfl_xor(best, s);
                int oi = __shfl_xor(bi, s);
                if (ov < best || (ov == best && oi < bi)) { best = ov; bi = oi; }
            }
            if ((tid & 15) == 0)
                idxb[(size_t)(t0 + th_t * 2 + r) * NCB + c] = (unsigned char)bi;
        }
    }
}

// ---- Launch B: out[t][o] = sum_c lut[c][idx[t][c]][o]  (bias already in lut) ----
// No LDS: lut (4 MB) is L2/L3-resident; gather directly with 128B-line-exact
// float4 loads (8 lanes x 16B contiguous per (t,c) row). 32 independent loads
// per token iteration -> deep MLP; occupancy limited only by VGPRs.
// Grid: blockIdx.x = o-tile (L2 locality: each XCD sees ~8 o-tiles = 512 KB of lut).
__global__ __launch_bounds__(256) void gather_kernel(const float* __restrict__ lut,
                                                     const unsigned char* __restrict__ idxb,
                                                     float* __restrict__ out) {
    const int o0 = blockIdx.x * 32;
    const int t0 = blockIdx.y * 128;
    const int og = threadIdx.x & 7;   // 8 o-groups of float4 -> 32 o per block
    const int tl = threadIdx.x >> 3;  // 0..31 tokens per iteration
    const int o = o0 + og * 4;

#pragma unroll
    for (int tt = 0; tt < 4; ++tt) {
        const int t = t0 + tt * 32 + tl;
        const uint4 iv0 = *(const uint4*)(idxb + (size_t)t * NCB);
        const uint4 iv1 = *(const uint4*)(idxb + (size_t)t * NCB + 16);
        unsigned int u[8] = {iv0.x, iv0.y, iv0.z, iv0.w, iv1.x, iv1.y, iv1.z, iv1.w};
        float4 acc = make_float4(0.f, 0.f, 0.f, 0.f);
#pragma unroll
        for (int c4 = 0; c4 < 8; ++c4) {
            unsigned int uv = u[c4];
#pragma unroll
            for (int b = 0; b < 4; ++b) {
                int cc = c4 * 4 + b;
                int k = (uv >> (8 * b)) & 0xff;
                const float4 v = *(const float4*)(lut + (size_t)(cc * KK + k) * OUT_F + o);
                acc.x += v.x; acc.y += v.y; acc.z += v.z; acc.w += v.w;
            }
        }
        *(float4*)(out + (size_t)t * OUT_F + o) = acc;
    }
}

extern "C" void kernel_launch(void* const* d_in, const int* in_sizes, int n_in,
                              void* d_out, int out_size, void* d_ws, size_t ws_size,
                              hipStream_t stream) {
    const float* x         = (const float*)d_in[0];  // [2,1024,4096]
    const float* centroids = (const float*)d_in[1];  // [32,16,128]
    const float* weight    = (const float*)d_in[2];  // [32,128,2048]
    const float* bias      = (const float*)d_in[4];  // [2048]
    float* out = (float*)d_out;                      // [2048,2048] fp32

    float* lut = (float*)d_ws;                                // 4 MB
    unsigned char* idxb = (unsigned char*)d_ws + (4u << 20);  // 64 KB

    fused_lut_idx<<<LUT_BLOCKS + IDX_BLOCKS, 256, 0, stream>>>(
        centroids, weight, x, bias, lut, idxb);
    gather_kernel<<<dim3(OUT_F / 32, NTOK / 128), 256, 0, stream>>>(lut, idxb, out);
}